// Round 16
// baseline (1895.486 us; speedup 1.0000x reference)
//
#include <hip/hip_runtime.h>
#include <math.h>

#define PI_F 3.14159265358979323846f
#define L2E  1.44269504088896340736f

typedef _Float16 half8 __attribute__((ext_vector_type(8)));
typedef _Float16 half4 __attribute__((ext_vector_type(4)));
typedef float f32x4 __attribute__((ext_vector_type(4)));

#define MFMA(a, b, c) __builtin_amdgcn_mfma_f32_16x16x32_f16(a, b, c, 0, 0, 0)
#define OFF_CAT 49152   // halfs: wcat starts after whh0 (3*128*128)

__device__ __forceinline__ float rcp_fast(float x) { return __builtin_amdgcn_rcpf(x); }
// Exp2-domain gates: pre-activations arrive PRE-SCALED (R/Z by log2e, N by
// 2*log2e, folded into the weights at prep) so v_exp_f32 is used directly
// with no per-call multiply.
__device__ __forceinline__ float sigmoid_y(float y) {   // y = x*log2e
    float e = exp2f(-y);
    return rcp_fast(1.0f + e);
}
__device__ __forceinline__ float tanh_y(float y) {      // y = 2x*log2e
    float ay = fabsf(y);
    float e  = exp2f(-ay);
    float t  = (1.0f - e) * rcp_fast(1.0f + e);
    return y >= 0.0f ? t : -t;
}

// Prep: f16 weights, gate-scaled (R/Z x log2e, N x 2log2e) BEFORE rounding;
// concat [w_ih1|w_hh1] along K for layer 1.
__global__ void prep_kernel(const float* __restrict__ whh0,
                            const float* __restrict__ wih1,
                            const float* __restrict__ whh1,
                            _Float16* __restrict__ wsp) {
    int i = blockIdx.x * 256 + threadIdx.x;
    if (i < 49152) {
        float sc = ((i >> 7) >= 256) ? (2.0f * L2E) : L2E;
        wsp[i] = (_Float16)(whh0[i] * sc);
    }
    if (i < 98304) {
        int n = i >> 8, k = i & 255;
        float v = (k < 128) ? wih1[(n << 7) + k] : whh1[(n << 7) + k - 128];
        float sc = (n >= 256) ? (2.0f * L2E) : L2E;
        wsp[OFF_CAT + i] = (_Float16)(v * sc);
    }
}

// 512 threads (8 waves), 128 elems/block, 1 block/CU (LDS 136KB), 2
// waves/SIMD, 256 regs. r15 structure (best, 1524us): 16 dims/wave both
// layers, weights resident (144 regs, "+v"-pinned), own-dim h state in f32
// registers, f16 h planes in LDS, 2 barriers/tick
//     { A: h0(t) | bar | B: h1(t) | bar | head(t) }.
// Falsified levers (do not revisit): barrier fusion (r3/r7/r9), layer-split
// waves (r6), AGPR pins (r10), half-tick interleave (r12), x-barrier
// prefetch (r13), distributed head (r14). Occupancy locked at 2 waves/SIMD
// (weight residency 144 regs x HW tier quantization at 128). LDS maxed.
//
// Round-16 change: EXP2-DOMAIN GATES (work reduction -- the only lever class
// that has ever won here: r8, r11, r15). Gate scale factors folded into the
// weights (prep) and gi0T (init): sigma/tanh then use v_exp_f32 directly,
// saving ~5 VALU ops per h-value (~4.5% of issue). hn refactored to
// nn + zz*(hp - nn). Numerics shift only at f16 weight-rounding level.
//
// h planes (128 elems) in MFMA-B-frag chunk order, double-buffered:
//   plane[buf][(kc*8 + eb)*512 + (qd*16 + l4)*8 + j] = h[e=eb*16+l4][dim=32kc+8qd+j]

__global__ void __launch_bounds__(512, 2) rnn_wf_pipe(
    const int*   __restrict__ x,
    const float* __restrict__ w_ih0,
    const float* __restrict__ w_lin,
    const float* __restrict__ b_lin,
    const _Float16* __restrict__ wsp,
    float*       __restrict__ out,
    int nbatch)
{
    __shared__ _Float16 h0[2][16384], h1[2][16384];
    __shared__ float gi0T[2][3][128];          // [prev-bit][gate][dim], gate-scaled
    __shared__ float wlinT[256];               // w_lin flat
    __shared__ unsigned long long bmk[128];    // per-element bit mask

    const int t    = threadIdx.x;
    const int wv   = t >> 6;                   // 0..7 = dim-block (16 dims)
    const int l4   = t & 15;
    const int q    = (t >> 4) & 3;
    const int ebg  = blockIdx.x * 128;

    // ---- init LDS ----
    for (int i = t; i < 16384; i += 512) {     // 16384 ints = 2 bufs x 16384 halfs per array
        ((int*)h0)[i] = 0; ((int*)h1)[i] = 0;
    }
    for (int i = t; i < 768; i += 512) {
        int b = i / 384, rem = i - b * 384;
        float sc = (rem >= 256) ? (2.0f * L2E) : L2E;
        ((float*)gi0T)[b * 384 + rem] = w_ih0[rem * 2 + b] * sc;
    }
    if (t < 256) wlinT[t] = w_lin[t];
    {   // bit masks: thread t -> element t>>2 (0..127), quarter t&3
        int el = t >> 2, qq = t & 3;
        int eg = ebg + el; if (eg >= nbatch) eg = nbatch - 1;
        const int* xr = x + (size_t)eg * 64 + qq * 16;
        unsigned long long m = 0ull;
#pragma unroll
        for (int i = 0; i < 16; ++i)
            m |= ((unsigned long long)((unsigned)(xr[i] + 1) >> 1)) << (qq * 16 + i);
        m |= __shfl_xor(m, 1);
        m |= __shfl_xor(m, 2);
        if (qq == 0) bmk[el] = m;
    }

    const int lo8 = ((q << 4) + l4) << 3;      // = lane*8 halfs: B-frag chunk offset
    const int d0  = wv * 16 + 4 * q;           // first of 4 dims this lane updates
    const int epb = (d0 >> 5) * 4096 + ((d0 >> 3) & 3) * 128 + l4 * 8 + (d0 & 7);

    // ---- register-resident weights (gate-scaled in prep) ----
    half8 w0[3][4];                            // 48 regs
#pragma unroll
    for (int g = 0; g < 3; ++g)
#pragma unroll
        for (int kc = 0; kc < 4; ++kc)
            w0[g][kc] = *(const half8*)(wsp + (size_t)(g * 128 + 16 * wv + l4) * 128 + 32 * kc + 8 * q);
    half8 w1[3][8];                            // 96 regs
#pragma unroll
    for (int g = 0; g < 3; ++g)
#pragma unroll
        for (int kc = 0; kc < 8; ++kc)
            w1[g][kc] = *(const half8*)(wsp + OFF_CAT + (size_t)(g * 128 + 16 * wv + l4) * 256 + 32 * kc + 8 * q);

    // ---- own-dim h state in f32 registers (statically indexed) ----
    f32x4 h0s[8], h1s[8];
#pragma unroll
    for (int eb = 0; eb < 8; ++eb) {
        h0s[eb] = (f32x4){0.f, 0.f, 0.f, 0.f};
        h1s[eb] = (f32x4){0.f, 0.f, 0.f, 0.f};
    }

    // head state (all 8 waves, q-replicated): wave wv owns elems wv*16..+15
    float amp = 1.0f, phs = 0.0f, nu = 0.0f, nd = 0.0f;
    const float bl0 = b_lin[0], bl1 = b_lin[1];
    const int eh = (wv << 4) + l4;

    __syncthreads();

    for (int tick = 0; tick < 64; ++tick) {
        const int cur = tick & 1, prv = cur ^ 1;

        // pin weights: opaque loop-carried registers (no remat from memory)
#pragma unroll
        for (int g = 0; g < 3; ++g) {
#pragma unroll
            for (int kc = 0; kc < 4; ++kc) asm volatile("" : "+v"(w0[g][kc]));
#pragma unroll
            for (int kc = 0; kc < 8; ++kc) asm volatile("" : "+v"(w1[g][kc]));
        }

        // ---- Phase A: h0(tick) = GRU0(onehot(bit(tick-1)), h0(tick-1)) ----
#pragma unroll
        for (int eb = 0; eb < 8; ++eb) {
            f32x4 aR = {0,0,0,0}, aZ = {0,0,0,0}, aN = {0,0,0,0};
#pragma unroll
            for (int kc = 0; kc < 4; ++kc) {
                const int cb = (kc * 8 + eb) * 512 + lo8;
                half8 hh = *(const half8*)&h0[prv][cb];
                aR = MFMA(w0[0][kc], hh, aR);
                aZ = MFMA(w0[1][kc], hh, aZ);
                aN = MFMA(w0[2][kc], hh, aN);
            }
            const int e = eb * 16 + l4;
            f32x4 giR = {0,0,0,0}, giZ = {0,0,0,0}, giN = {0,0,0,0};
            if (tick > 0) {
                int pb = (int)((bmk[e] >> (tick - 1)) & 1ull);
                const float* gp = &gi0T[pb][0][0];
                giR = *(const f32x4*)(gp + d0);
                giZ = *(const f32x4*)(gp + 128 + d0);
                giN = *(const f32x4*)(gp + 256 + d0);
            }
            const int ep_ = epb + eb * 512;
            f32x4 hp = h0s[eb];
            f32x4 hnv;
            half4 nh;
#pragma unroll
            for (int r = 0; r < 4; ++r) {
                float rr = sigmoid_y(giR[r] + aR[r]);
                float zz = sigmoid_y(giZ[r] + aZ[r]);
                float nn = tanh_y(giN[r] + rr * aN[r]);
                float hn = nn + zz * (hp[r] - nn);
                hnv[r] = hn;
                nh[r] = (_Float16)hn;
            }
            h0s[eb] = hnv;
            *(half4*)&h0[cur][ep_] = nh;
        }

        __syncthreads();

        // ---- Phase B: h1(tick) = GRU1(h0(tick), h1(tick-1)) ----
#pragma unroll
        for (int eb = 0; eb < 8; ++eb) {
            f32x4 aR = {0,0,0,0}, aZ = {0,0,0,0};
            f32x4 aNi = {0,0,0,0}, aNh = {0,0,0,0};
#pragma unroll
            for (int kc = 0; kc < 8; ++kc) {
                const int cb = ((kc & 3) * 8 + eb) * 512 + lo8;
                half8 hh;
                if (kc < 4) hh = *(const half8*)&h0[cur][cb];
                else        hh = *(const half8*)&h1[prv][cb];
                aR = MFMA(w1[0][kc], hh, aR);
                aZ = MFMA(w1[1][kc], hh, aZ);
                if (kc < 4) aNi = MFMA(w1[2][kc], hh, aNi);
                else        aNh = MFMA(w1[2][kc], hh, aNh);
            }
            const int ep_ = epb + eb * 512;
            f32x4 hp = h1s[eb];
            f32x4 hnv;
            half4 nh;
#pragma unroll
            for (int r = 0; r < 4; ++r) {
                float rr = sigmoid_y(aR[r]);
                float zz = sigmoid_y(aZ[r]);
                float nn = tanh_y(aNi[r] + rr * aNh[r]);
                float hn = nn + zz * (hp[r] - nn);
                hnv[r] = hn;
                nh[r] = (_Float16)hn;
            }
            h1s[eb] = hnv;
            *(half4*)&h1[cur][ep_] = nh;
        }

        __syncthreads();

        // ---- head for step s = tick; h1(s) in buf cur.  ALL 8 waves, each
        //      owning its 16 elems. Lane-linear reads (conflict-free);
        //      xor-16/32 reduce combines q-groups. ----
        {
            const int s = tick;
            float l0 = 0.0f, l1 = 0.0f;
#pragma unroll
            for (int ks = 0; ks < 4; ++ks) {
                const int cb = (ks * 8 + wv) * 512 + lo8;
                half8 hh = *(const half8*)&h1[cur][cb];
                const float* wpl = &wlinT[32 * ks + 8 * q];
#pragma unroll
                for (int j = 0; j < 8; ++j) {
                    float hv = (float)hh[j];
                    l0 = fmaf(hv, wpl[j], l0);
                    l1 = fmaf(hv, wpl[128 + j], l1);
                }
            }
            l0 += __shfl_xor(l0, 16); l0 += __shfl_xor(l0, 32); l0 += bl0;
            l1 += __shfl_xor(l1, 16); l1 += __shfl_xor(l1, 32); l1 += bl1;

            // head keeps exact reference-form math (unscaled logits)
            float e01 = __expf(-(l0 - l1));
            float p0 = rcp_fast(1.0f + e01);
            float e10 = __expf(-(l1 - l0));
            float p1 = rcp_fast(1.0f + e10);
            float y0 = sqrtf(p0), y1 = sqrtf(p1);
            float ph0 = PI_F * l0 * rcp_fast(1.0f + fabsf(l0));
            float ph1 = PI_F * l1 * rcp_fast(1.0f + fabsf(l1));

            int bit = (int)((bmk[eh] >> s) & 1ull);
            bool is_even = (s & 1) == 0;
            float num   = is_even ? nu : nd;
            float lower = -16.0f + (float)(s >> 1);
            float occ   = (num < 16.0f) ? 1.0f : 0.0f;
            float unocc = (num > lower) ? 1.0f : 0.0f;
            if (s >= 16) {
                float m0 = y0 * unocc, m1 = y1 * occ;
                float nrm = fmaxf(sqrtf(m0 * m0 + m1 * m1), 1e-12f);
                float rn  = rcp_fast(nrm);
                y0 = m0 * rn; y1 = m1 * rn;
            }
            if (is_even) nu += (float)bit; else nd += (float)bit;
            amp *= bit ? y1 : y0;
            phs += bit ? ph1 : ph0;
        }
    }

    if (q == 0) {
        int eg = ebg + eh;
        if (eg < nbatch) {
            float s, c;
            sincosf(phs, &s, &c);
            out[eg]          = amp * c;
            out[nbatch + eg] = amp * s;
        }
    }
}

extern "C" void kernel_launch(void* const* d_in, const int* in_sizes, int n_in,
                              void* d_out, int out_size, void* d_ws, size_t ws_size,
                              hipStream_t stream) {
    const int*   x     = (const int*)  d_in[0];
    const float* w_ih0 = (const float*)d_in[1];
    const float* w_hh0 = (const float*)d_in[2];
    const float* w_ih1 = (const float*)d_in[3];
    const float* w_hh1 = (const float*)d_in[4];
    const float* w_lin = (const float*)d_in[5];
    const float* b_lin = (const float*)d_in[6];
    float* out = (float*)d_out;
    _Float16* wsp = (_Float16*)d_ws;

    const int nbatch = in_sizes[0] / 64;

    prep_kernel<<<384, 256, 0, stream>>>(w_hh0, w_ih1, w_hh1, wsp);

    const int blocks = (nbatch + 127) / 128;
    rnn_wf_pipe<<<blocks, 512, 0, stream>>>(x, w_ih0, w_lin, b_lin, wsp, out, nbatch);
}

// Round 17
// 1437.324 us; speedup vs baseline: 1.3188x; 1.3188x over previous
//
#include <hip/hip_runtime.h>
#include <math.h>

#define PI_F 3.14159265358979323846f
#define L2E  1.44269504088896340736f

typedef _Float16 half8 __attribute__((ext_vector_type(8)));
typedef _Float16 half4 __attribute__((ext_vector_type(4)));
typedef float f32x4 __attribute__((ext_vector_type(4)));

#define MFMA(a, b, c) __builtin_amdgcn_mfma_f32_16x16x32_f16(a, b, c, 0, 0, 0)
#define OFF_CAT 49152   // halfs: wcat starts after whh0 (3*128*128)

__device__ __forceinline__ float rcp_fast(float x) { return __builtin_amdgcn_rcpf(x); }
__device__ __forceinline__ float exp2_fast(float x) { return __builtin_amdgcn_exp2f(x); }
// Exp2-domain gates: pre-activations arrive PRE-SCALED (R/Z by log2e, N by
// 2*log2e, folded into the weights at prep). exp2_fast lowers to exactly one
// v_exp_f32 (r16 lesson: plain exp2f() is the PRECISE OCML expansion --
// multi-inst + spill, a 24% regression; __builtin_amdgcn_exp2f is the raw
// instruction).
__device__ __forceinline__ float sigmoid_y(float y) {   // y = x*log2e
    float e = exp2_fast(-y);
    return rcp_fast(1.0f + e);
}
__device__ __forceinline__ float tanh_y(float y) {      // y = 2x*log2e
    float ay = fabsf(y);
    float e  = exp2_fast(-ay);
    float t  = (1.0f - e) * rcp_fast(1.0f + e);
    return y >= 0.0f ? t : -t;
}

// Prep: f16 weights, gate-scaled (R/Z x log2e, N x 2log2e) BEFORE rounding;
// concat [w_ih1|w_hh1] along K for layer 1.
__global__ void prep_kernel(const float* __restrict__ whh0,
                            const float* __restrict__ wih1,
                            const float* __restrict__ whh1,
                            _Float16* __restrict__ wsp) {
    int i = blockIdx.x * 256 + threadIdx.x;
    if (i < 49152) {
        float sc = ((i >> 7) >= 256) ? (2.0f * L2E) : L2E;
        wsp[i] = (_Float16)(whh0[i] * sc);
    }
    if (i < 98304) {
        int n = i >> 8, k = i & 255;
        float v = (k < 128) ? wih1[(n << 7) + k] : whh1[(n << 7) + k - 128];
        float sc = (n >= 256) ? (2.0f * L2E) : L2E;
        wsp[OFF_CAT + i] = (_Float16)(v * sc);
    }
}

// 512 threads (8 waves), 128 elems/block, 1 block/CU (LDS 136KB), 2
// waves/SIMD, 256 regs. r15 structure (best, 1524us): 16 dims/wave both
// layers, weights resident (144 regs, "+v"-pinned), own-dim h state in f32
// registers, f16 h planes in LDS, 2 barriers/tick
//     { A: h0(t) | bar | B: h1(t) | bar | head(t) }.
// Falsified levers (do not revisit): barrier fusion (r3/r7/r9), layer-split
// waves (r6), AGPR pins (r10), half-tick interleave (r12), x-barrier
// prefetch (r13), distributed head (r14), library exp2f (r16). Occupancy
// locked at 2 waves/SIMD; LDS maxed.
//
// Round-17: exp2-domain gates done RIGHT -- scale factors folded into the
// f16 weights (prep) and gi0T (init); sigma/tanh use __builtin_amdgcn_exp2f
// (one v_exp_f32). Saves ~4 VALU per h-value (~2% of wall). hn refactored
// to nn + zz*(hp - nn). Head keeps reference-form math.
//
// h planes (128 elems) in MFMA-B-frag chunk order, double-buffered:
//   plane[buf][(kc*8 + eb)*512 + (qd*16 + l4)*8 + j] = h[e=eb*16+l4][dim=32kc+8qd+j]

__global__ void __launch_bounds__(512, 2) rnn_wf_pipe(
    const int*   __restrict__ x,
    const float* __restrict__ w_ih0,
    const float* __restrict__ w_lin,
    const float* __restrict__ b_lin,
    const _Float16* __restrict__ wsp,
    float*       __restrict__ out,
    int nbatch)
{
    __shared__ _Float16 h0[2][16384], h1[2][16384];
    __shared__ float gi0T[2][3][128];          // [prev-bit][gate][dim], gate-scaled
    __shared__ float wlinT[256];               // w_lin flat
    __shared__ unsigned long long bmk[128];    // per-element bit mask

    const int t    = threadIdx.x;
    const int wv   = t >> 6;                   // 0..7 = dim-block (16 dims)
    const int l4   = t & 15;
    const int q    = (t >> 4) & 3;
    const int ebg  = blockIdx.x * 128;

    // ---- init LDS ----
    for (int i = t; i < 16384; i += 512) {     // 16384 ints = 2 bufs x 16384 halfs per array
        ((int*)h0)[i] = 0; ((int*)h1)[i] = 0;
    }
    for (int i = t; i < 768; i += 512) {
        int b = i / 384, rem = i - b * 384;
        float sc = (rem >= 256) ? (2.0f * L2E) : L2E;
        ((float*)gi0T)[b * 384 + rem] = w_ih0[rem * 2 + b] * sc;
    }
    if (t < 256) wlinT[t] = w_lin[t];
    {   // bit masks: thread t -> element t>>2 (0..127), quarter t&3
        int el = t >> 2, qq = t & 3;
        int eg = ebg + el; if (eg >= nbatch) eg = nbatch - 1;
        const int* xr = x + (size_t)eg * 64 + qq * 16;
        unsigned long long m = 0ull;
#pragma unroll
        for (int i = 0; i < 16; ++i)
            m |= ((unsigned long long)((unsigned)(xr[i] + 1) >> 1)) << (qq * 16 + i);
        m |= __shfl_xor(m, 1);
        m |= __shfl_xor(m, 2);
        if (qq == 0) bmk[el] = m;
    }

    const int lo8 = ((q << 4) + l4) << 3;      // = lane*8 halfs: B-frag chunk offset
    const int d0  = wv * 16 + 4 * q;           // first of 4 dims this lane updates
    const int epb = (d0 >> 5) * 4096 + ((d0 >> 3) & 3) * 128 + l4 * 8 + (d0 & 7);

    // ---- register-resident weights (gate-scaled in prep) ----
    half8 w0[3][4];                            // 48 regs
#pragma unroll
    for (int g = 0; g < 3; ++g)
#pragma unroll
        for (int kc = 0; kc < 4; ++kc)
            w0[g][kc] = *(const half8*)(wsp + (size_t)(g * 128 + 16 * wv + l4) * 128 + 32 * kc + 8 * q);
    half8 w1[3][8];                            // 96 regs
#pragma unroll
    for (int g = 0; g < 3; ++g)
#pragma unroll
        for (int kc = 0; kc < 8; ++kc)
            w1[g][kc] = *(const half8*)(wsp + OFF_CAT + (size_t)(g * 128 + 16 * wv + l4) * 256 + 32 * kc + 8 * q);

    // ---- own-dim h state in f32 registers (statically indexed) ----
    f32x4 h0s[8], h1s[8];
#pragma unroll
    for (int eb = 0; eb < 8; ++eb) {
        h0s[eb] = (f32x4){0.f, 0.f, 0.f, 0.f};
        h1s[eb] = (f32x4){0.f, 0.f, 0.f, 0.f};
    }

    // head state (all 8 waves, q-replicated): wave wv owns elems wv*16..+15
    float amp = 1.0f, phs = 0.0f, nu = 0.0f, nd = 0.0f;
    const float bl0 = b_lin[0], bl1 = b_lin[1];
    const int eh = (wv << 4) + l4;

    __syncthreads();

    for (int tick = 0; tick < 64; ++tick) {
        const int cur = tick & 1, prv = cur ^ 1;

        // pin weights: opaque loop-carried registers (no remat from memory)
#pragma unroll
        for (int g = 0; g < 3; ++g) {
#pragma unroll
            for (int kc = 0; kc < 4; ++kc) asm volatile("" : "+v"(w0[g][kc]));
#pragma unroll
            for (int kc = 0; kc < 8; ++kc) asm volatile("" : "+v"(w1[g][kc]));
        }

        // ---- Phase A: h0(tick) = GRU0(onehot(bit(tick-1)), h0(tick-1)) ----
#pragma unroll
        for (int eb = 0; eb < 8; ++eb) {
            f32x4 aR = {0,0,0,0}, aZ = {0,0,0,0}, aN = {0,0,0,0};
#pragma unroll
            for (int kc = 0; kc < 4; ++kc) {
                const int cb = (kc * 8 + eb) * 512 + lo8;
                half8 hh = *(const half8*)&h0[prv][cb];
                aR = MFMA(w0[0][kc], hh, aR);
                aZ = MFMA(w0[1][kc], hh, aZ);
                aN = MFMA(w0[2][kc], hh, aN);
            }
            const int e = eb * 16 + l4;
            f32x4 giR = {0,0,0,0}, giZ = {0,0,0,0}, giN = {0,0,0,0};
            if (tick > 0) {
                int pb = (int)((bmk[e] >> (tick - 1)) & 1ull);
                const float* gp = &gi0T[pb][0][0];
                giR = *(const f32x4*)(gp + d0);
                giZ = *(const f32x4*)(gp + 128 + d0);
                giN = *(const f32x4*)(gp + 256 + d0);
            }
            const int ep_ = epb + eb * 512;
            f32x4 hp = h0s[eb];
            f32x4 hnv;
            half4 nh;
#pragma unroll
            for (int r = 0; r < 4; ++r) {
                float rr = sigmoid_y(giR[r] + aR[r]);
                float zz = sigmoid_y(giZ[r] + aZ[r]);
                float nn = tanh_y(giN[r] + rr * aN[r]);
                float hn = nn + zz * (hp[r] - nn);
                hnv[r] = hn;
                nh[r] = (_Float16)hn;
            }
            h0s[eb] = hnv;
            *(half4*)&h0[cur][ep_] = nh;
        }

        __syncthreads();

        // ---- Phase B: h1(tick) = GRU1(h0(tick), h1(tick-1)) ----
#pragma unroll
        for (int eb = 0; eb < 8; ++eb) {
            f32x4 aR = {0,0,0,0}, aZ = {0,0,0,0};
            f32x4 aNi = {0,0,0,0}, aNh = {0,0,0,0};
#pragma unroll
            for (int kc = 0; kc < 8; ++kc) {
                const int cb = ((kc & 3) * 8 + eb) * 512 + lo8;
                half8 hh;
                if (kc < 4) hh = *(const half8*)&h0[cur][cb];
                else        hh = *(const half8*)&h1[prv][cb];
                aR = MFMA(w1[0][kc], hh, aR);
                aZ = MFMA(w1[1][kc], hh, aZ);
                if (kc < 4) aNi = MFMA(w1[2][kc], hh, aNi);
                else        aNh = MFMA(w1[2][kc], hh, aNh);
            }
            const int ep_ = epb + eb * 512;
            f32x4 hp = h1s[eb];
            f32x4 hnv;
            half4 nh;
#pragma unroll
            for (int r = 0; r < 4; ++r) {
                float rr = sigmoid_y(aR[r]);
                float zz = sigmoid_y(aZ[r]);
                float nn = tanh_y(aNi[r] + rr * aNh[r]);
                float hn = nn + zz * (hp[r] - nn);
                hnv[r] = hn;
                nh[r] = (_Float16)hn;
            }
            h1s[eb] = hnv;
            *(half4*)&h1[cur][ep_] = nh;
        }

        __syncthreads();

        // ---- head for step s = tick; h1(s) in buf cur.  ALL 8 waves, each
        //      owning its 16 elems. Lane-linear reads (conflict-free);
        //      xor-16/32 reduce combines q-groups. ----
        {
            const int s = tick;
            float l0 = 0.0f, l1 = 0.0f;
#pragma unroll
            for (int ks = 0; ks < 4; ++ks) {
                const int cb = (ks * 8 + wv) * 512 + lo8;
                half8 hh = *(const half8*)&h1[cur][cb];
                const float* wpl = &wlinT[32 * ks + 8 * q];
#pragma unroll
                for (int j = 0; j < 8; ++j) {
                    float hv = (float)hh[j];
                    l0 = fmaf(hv, wpl[j], l0);
                    l1 = fmaf(hv, wpl[128 + j], l1);
                }
            }
            l0 += __shfl_xor(l0, 16); l0 += __shfl_xor(l0, 32); l0 += bl0;
            l1 += __shfl_xor(l1, 16); l1 += __shfl_xor(l1, 32); l1 += bl1;

            // head keeps exact reference-form math (unscaled logits)
            float e01 = __expf(-(l0 - l1));
            float p0 = rcp_fast(1.0f + e01);
            float e10 = __expf(-(l1 - l0));
            float p1 = rcp_fast(1.0f + e10);
            float y0 = sqrtf(p0), y1 = sqrtf(p1);
            float ph0 = PI_F * l0 * rcp_fast(1.0f + fabsf(l0));
            float ph1 = PI_F * l1 * rcp_fast(1.0f + fabsf(l1));

            int bit = (int)((bmk[eh] >> s) & 1ull);
            bool is_even = (s & 1) == 0;
            float num   = is_even ? nu : nd;
            float lower = -16.0f + (float)(s >> 1);
            float occ   = (num < 16.0f) ? 1.0f : 0.0f;
            float unocc = (num > lower) ? 1.0f : 0.0f;
            if (s >= 16) {
                float m0 = y0 * unocc, m1 = y1 * occ;
                float nrm = fmaxf(sqrtf(m0 * m0 + m1 * m1), 1e-12f);
                float rn  = rcp_fast(nrm);
                y0 = m0 * rn; y1 = m1 * rn;
            }
            if (is_even) nu += (float)bit; else nd += (float)bit;
            amp *= bit ? y1 : y0;
            phs += bit ? ph1 : ph0;
        }
    }

    if (q == 0) {
        int eg = ebg + eh;
        if (eg < nbatch) {
            float s, c;
            sincosf(phs, &s, &c);
            out[eg]          = amp * c;
            out[nbatch + eg] = amp * s;
        }
    }
}

extern "C" void kernel_launch(void* const* d_in, const int* in_sizes, int n_in,
                              void* d_out, int out_size, void* d_ws, size_t ws_size,
                              hipStream_t stream) {
    const int*   x     = (const int*)  d_in[0];
    const float* w_ih0 = (const float*)d_in[1];
    const float* w_hh0 = (const float*)d_in[2];
    const float* w_ih1 = (const float*)d_in[3];
    const float* w_hh1 = (const float*)d_in[4];
    const float* w_lin = (const float*)d_in[5];
    const float* b_lin = (const float*)d_in[6];
    float* out = (float*)d_out;
    _Float16* wsp = (_Float16*)d_ws;

    const int nbatch = in_sizes[0] / 64;

    prep_kernel<<<384, 256, 0, stream>>>(w_hh0, w_ih1, w_hh1, wsp);

    const int blocks = (nbatch + 127) / 128;
    rnn_wf_pipe<<<blocks, 512, 0, stream>>>(x, w_ih0, w_lin, b_lin, wsp, out, nbatch);
}

// Round 19
// 1344.139 us; speedup vs baseline: 1.4102x; 1.0693x over previous
//
#include <hip/hip_runtime.h>
#include <math.h>

#define PI_F 3.14159265358979323846f
#define L2E  1.44269504088896340736f

typedef _Float16 half8 __attribute__((ext_vector_type(8)));
typedef _Float16 half4 __attribute__((ext_vector_type(4)));
typedef _Float16 half2t __attribute__((ext_vector_type(2)));
typedef float f32x4 __attribute__((ext_vector_type(4)));

#define MFMA(a, b, c) __builtin_amdgcn_mfma_f32_16x16x32_f16(a, b, c, 0, 0, 0)
#define OFF_CAT 49152   // halfs: wcat starts after whh0 (3*128*128)
// cvt_pkrtz returns __fp16 ext_vector(2); bit_cast to our _Float16 pair
// (layout-identical) -- r18 lesson: implicit conversion is a compile error.
#define CVT_PK(a, b) __builtin_bit_cast(half2t, __builtin_amdgcn_cvt_pkrtz((a), (b)))

__device__ __forceinline__ float rcp_fast(float x) { return __builtin_amdgcn_rcpf(x); }
__device__ __forceinline__ float exp2_fast(float x) { return __builtin_amdgcn_exp2f(x); }
// Exp2-domain gates: pre-activations arrive PRE-SCALED (R/Z by log2e, N by
// 2*log2e, folded into the weights at prep). exp2_fast lowers to one
// v_exp_f32 (r16 lesson: library exp2f() is the precise OCML expansion --
// multi-inst + spill, 24% regression).
__device__ __forceinline__ float sigmoid_y(float y) {   // y = x*log2e
    float e = exp2_fast(-y);                            // neg = free src modifier
    return rcp_fast(1.0f + e);
}
// tanh via 2*sigma(2x)-1 -- 4 ops (exp2, add, rcp, fma), no abs/select.
// Limits: y->-inf => e=inf => rcp=0 => -1; y->+inf => e=0 => +1. Exact at 0.
__device__ __forceinline__ float tanh_y(float y) {      // y = 2x*log2e
    float e = exp2_fast(-y);
    return fmaf(2.0f, rcp_fast(1.0f + e), -1.0f);
}

// Prep: f16 weights, gate-scaled (R/Z x log2e, N x 2log2e) BEFORE rounding;
// concat [w_ih1|w_hh1] along K for layer 1.
__global__ void prep_kernel(const float* __restrict__ whh0,
                            const float* __restrict__ wih1,
                            const float* __restrict__ whh1,
                            _Float16* __restrict__ wsp) {
    int i = blockIdx.x * 256 + threadIdx.x;
    if (i < 49152) {
        float sc = ((i >> 7) >= 256) ? (2.0f * L2E) : L2E;
        wsp[i] = (_Float16)(whh0[i] * sc);
    }
    if (i < 98304) {
        int n = i >> 8, k = i & 255;
        float v = (k < 128) ? wih1[(n << 7) + k] : whh1[(n << 7) + k - 128];
        float sc = (n >= 256) ? (2.0f * L2E) : L2E;
        wsp[OFF_CAT + i] = (_Float16)(v * sc);
    }
}

// 512 threads (8 waves), 128 elems/block, 1 block/CU (LDS 136KB), 2
// waves/SIMD, 256 regs. r17 structure (best, 1437us): 16 dims/wave both
// layers, weights resident (144 regs, "+v"-pinned), own-dim h state in f32
// registers, f16 h planes in LDS, exp2-domain gates, 2 barriers/tick
//     { A: h0(t) | bar | B: h1(t) | bar | head(t) }.
// Falsified levers (do not revisit): barrier fusion (r3/r7/r9), layer-split
// waves (r6), AGPR pins (r10), half-tick interleave (r12), x-barrier
// prefetch (r13), distributed head (r14), library exp2f (r16). Occupancy
// locked at 2 waves/SIMD; LDS maxed. Winning lever class: work reduction
// (r8 -29%, r11 -7%, r15 -1%, r17 -6%).
//
// Round-19 (= r18 retry, bit_cast fix): two epilogue micro-cuts:
//  1. tanh via 2*sigma-1 (4 ops, no cndmask) -- see tanh_y above.
//  2. h->f16 conversion via v_cvt_pkrtz_f16_f32 (2 f32 -> packed f16 pair in
//     one inst; halves the per-eb cvt count). RTZ differs from RTE by <=1
//     f16 ulp and only perturbs the MFMA operand; f32 state untouched.
//
// h planes (128 elems) in MFMA-B-frag chunk order, double-buffered:
//   plane[buf][(kc*8 + eb)*512 + (qd*16 + l4)*8 + j] = h[e=eb*16+l4][dim=32kc+8qd+j]

__global__ void __launch_bounds__(512, 2) rnn_wf_pipe(
    const int*   __restrict__ x,
    const float* __restrict__ w_ih0,
    const float* __restrict__ w_lin,
    const float* __restrict__ b_lin,
    const _Float16* __restrict__ wsp,
    float*       __restrict__ out,
    int nbatch)
{
    __shared__ _Float16 h0[2][16384], h1[2][16384];
    __shared__ float gi0T[2][3][128];          // [prev-bit][gate][dim], gate-scaled
    __shared__ float wlinT[256];               // w_lin flat
    __shared__ unsigned long long bmk[128];    // per-element bit mask

    const int t    = threadIdx.x;
    const int wv   = t >> 6;                   // 0..7 = dim-block (16 dims)
    const int l4   = t & 15;
    const int q    = (t >> 4) & 3;
    const int ebg  = blockIdx.x * 128;

    // ---- init LDS ----
    for (int i = t; i < 16384; i += 512) {     // 16384 ints = 2 bufs x 16384 halfs per array
        ((int*)h0)[i] = 0; ((int*)h1)[i] = 0;
    }
    for (int i = t; i < 768; i += 512) {
        int b = i / 384, rem = i - b * 384;
        float sc = (rem >= 256) ? (2.0f * L2E) : L2E;
        ((float*)gi0T)[b * 384 + rem] = w_ih0[rem * 2 + b] * sc;
    }
    if (t < 256) wlinT[t] = w_lin[t];
    {   // bit masks: thread t -> element t>>2 (0..127), quarter t&3
        int el = t >> 2, qq = t & 3;
        int eg = ebg + el; if (eg >= nbatch) eg = nbatch - 1;
        const int* xr = x + (size_t)eg * 64 + qq * 16;
        unsigned long long m = 0ull;
#pragma unroll
        for (int i = 0; i < 16; ++i)
            m |= ((unsigned long long)((unsigned)(xr[i] + 1) >> 1)) << (qq * 16 + i);
        m |= __shfl_xor(m, 1);
        m |= __shfl_xor(m, 2);
        if (qq == 0) bmk[el] = m;
    }

    const int lo8 = ((q << 4) + l4) << 3;      // = lane*8 halfs: B-frag chunk offset
    const int d0  = wv * 16 + 4 * q;           // first of 4 dims this lane updates
    const int epb = (d0 >> 5) * 4096 + ((d0 >> 3) & 3) * 128 + l4 * 8 + (d0 & 7);

    // ---- register-resident weights (gate-scaled in prep) ----
    half8 w0[3][4];                            // 48 regs
#pragma unroll
    for (int g = 0; g < 3; ++g)
#pragma unroll
        for (int kc = 0; kc < 4; ++kc)
            w0[g][kc] = *(const half8*)(wsp + (size_t)(g * 128 + 16 * wv + l4) * 128 + 32 * kc + 8 * q);
    half8 w1[3][8];                            // 96 regs
#pragma unroll
    for (int g = 0; g < 3; ++g)
#pragma unroll
        for (int kc = 0; kc < 8; ++kc)
            w1[g][kc] = *(const half8*)(wsp + OFF_CAT + (size_t)(g * 128 + 16 * wv + l4) * 256 + 32 * kc + 8 * q);

    // ---- own-dim h state in f32 registers (statically indexed) ----
    f32x4 h0s[8], h1s[8];
#pragma unroll
    for (int eb = 0; eb < 8; ++eb) {
        h0s[eb] = (f32x4){0.f, 0.f, 0.f, 0.f};
        h1s[eb] = (f32x4){0.f, 0.f, 0.f, 0.f};
    }

    // head state (all 8 waves, q-replicated): wave wv owns elems wv*16..+15
    float amp = 1.0f, phs = 0.0f, nu = 0.0f, nd = 0.0f;
    const float bl0 = b_lin[0], bl1 = b_lin[1];
    const int eh = (wv << 4) + l4;

    __syncthreads();

    for (int tick = 0; tick < 64; ++tick) {
        const int cur = tick & 1, prv = cur ^ 1;

        // pin weights: opaque loop-carried registers (no remat from memory)
#pragma unroll
        for (int g = 0; g < 3; ++g) {
#pragma unroll
            for (int kc = 0; kc < 4; ++kc) asm volatile("" : "+v"(w0[g][kc]));
#pragma unroll
            for (int kc = 0; kc < 8; ++kc) asm volatile("" : "+v"(w1[g][kc]));
        }

        // ---- Phase A: h0(tick) = GRU0(onehot(bit(tick-1)), h0(tick-1)) ----
#pragma unroll
        for (int eb = 0; eb < 8; ++eb) {
            f32x4 aR = {0,0,0,0}, aZ = {0,0,0,0}, aN = {0,0,0,0};
#pragma unroll
            for (int kc = 0; kc < 4; ++kc) {
                const int cb = (kc * 8 + eb) * 512 + lo8;
                half8 hh = *(const half8*)&h0[prv][cb];
                aR = MFMA(w0[0][kc], hh, aR);
                aZ = MFMA(w0[1][kc], hh, aZ);
                aN = MFMA(w0[2][kc], hh, aN);
            }
            const int e = eb * 16 + l4;
            f32x4 giR = {0,0,0,0}, giZ = {0,0,0,0}, giN = {0,0,0,0};
            if (tick > 0) {
                int pb = (int)((bmk[e] >> (tick - 1)) & 1ull);
                const float* gp = &gi0T[pb][0][0];
                giR = *(const f32x4*)(gp + d0);
                giZ = *(const f32x4*)(gp + 128 + d0);
                giN = *(const f32x4*)(gp + 256 + d0);
            }
            const int ep_ = epb + eb * 512;
            f32x4 hp = h0s[eb];
            f32x4 hnv;
#pragma unroll
            for (int r = 0; r < 4; ++r) {
                float rr = sigmoid_y(giR[r] + aR[r]);
                float zz = sigmoid_y(giZ[r] + aZ[r]);
                float nn = tanh_y(giN[r] + rr * aN[r]);
                hnv[r] = nn + zz * (hp[r] - nn);
            }
            h0s[eb] = hnv;
            half2t pa  = CVT_PK(hnv[0], hnv[1]);
            half2t pb2 = CVT_PK(hnv[2], hnv[3]);
            half4 nh;
            nh[0] = pa[0]; nh[1] = pa[1]; nh[2] = pb2[0]; nh[3] = pb2[1];
            *(half4*)&h0[cur][ep_] = nh;
        }

        __syncthreads();

        // ---- Phase B: h1(tick) = GRU1(h0(tick), h1(tick-1)) ----
#pragma unroll
        for (int eb = 0; eb < 8; ++eb) {
            f32x4 aR = {0,0,0,0}, aZ = {0,0,0,0};
            f32x4 aNi = {0,0,0,0}, aNh = {0,0,0,0};
#pragma unroll
            for (int kc = 0; kc < 8; ++kc) {
                const int cb = ((kc & 3) * 8 + eb) * 512 + lo8;
                half8 hh;
                if (kc < 4) hh = *(const half8*)&h0[cur][cb];
                else        hh = *(const half8*)&h1[prv][cb];
                aR = MFMA(w1[0][kc], hh, aR);
                aZ = MFMA(w1[1][kc], hh, aZ);
                if (kc < 4) aNi = MFMA(w1[2][kc], hh, aNi);
                else        aNh = MFMA(w1[2][kc], hh, aNh);
            }
            const int ep_ = epb + eb * 512;
            f32x4 hp = h1s[eb];
            f32x4 hnv;
#pragma unroll
            for (int r = 0; r < 4; ++r) {
                float rr = sigmoid_y(aR[r]);
                float zz = sigmoid_y(aZ[r]);
                float nn = tanh_y(aNi[r] + rr * aNh[r]);
                hnv[r] = nn + zz * (hp[r] - nn);
            }
            h1s[eb] = hnv;
            half2t pa  = CVT_PK(hnv[0], hnv[1]);
            half2t pb2 = CVT_PK(hnv[2], hnv[3]);
            half4 nh;
            nh[0] = pa[0]; nh[1] = pa[1]; nh[2] = pb2[0]; nh[3] = pb2[1];
            *(half4*)&h1[cur][ep_] = nh;
        }

        __syncthreads();

        // ---- head for step s = tick; h1(s) in buf cur.  ALL 8 waves, each
        //      owning its 16 elems. Lane-linear reads (conflict-free);
        //      xor-16/32 reduce combines q-groups. ----
        {
            const int s = tick;
            float l0 = 0.0f, l1 = 0.0f;
#pragma unroll
            for (int ks = 0; ks < 4; ++ks) {
                const int cb = (ks * 8 + wv) * 512 + lo8;
                half8 hh = *(const half8*)&h1[cur][cb];
                const float* wpl = &wlinT[32 * ks + 8 * q];
#pragma unroll
                for (int j = 0; j < 8; ++j) {
                    float hv = (float)hh[j];
                    l0 = fmaf(hv, wpl[j], l0);
                    l1 = fmaf(hv, wpl[128 + j], l1);
                }
            }
            l0 += __shfl_xor(l0, 16); l0 += __shfl_xor(l0, 32); l0 += bl0;
            l1 += __shfl_xor(l1, 16); l1 += __shfl_xor(l1, 32); l1 += bl1;

            // head keeps exact reference-form math (unscaled logits)
            float e01 = __expf(-(l0 - l1));
            float p0 = rcp_fast(1.0f + e01);
            float e10 = __expf(-(l1 - l0));
            float p1 = rcp_fast(1.0f + e10);
            float y0 = sqrtf(p0), y1 = sqrtf(p1);
            float ph0 = PI_F * l0 * rcp_fast(1.0f + fabsf(l0));
            float ph1 = PI_F * l1 * rcp_fast(1.0f + fabsf(l1));

            int bit = (int)((bmk[eh] >> s) & 1ull);
            bool is_even = (s & 1) == 0;
            float num   = is_even ? nu : nd;
            float lower = -16.0f + (float)(s >> 1);
            float occ   = (num < 16.0f) ? 1.0f : 0.0f;
            float unocc = (num > lower) ? 1.0f : 0.0f;
            if (s >= 16) {
                float m0 = y0 * unocc, m1 = y1 * occ;
                float nrm = fmaxf(sqrtf(m0 * m0 + m1 * m1), 1e-12f);
                float rn  = rcp_fast(nrm);
                y0 = m0 * rn; y1 = m1 * rn;
            }
            if (is_even) nu += (float)bit; else nd += (float)bit;
            amp *= bit ? y1 : y0;
            phs += bit ? ph1 : ph0;
        }
    }

    if (q == 0) {
        int eg = ebg + eh;
        if (eg < nbatch) {
            float s, c;
            sincosf(phs, &s, &c);
            out[eg]          = amp * c;
            out[nbatch + eg] = amp * s;
        }
    }
}

extern "C" void kernel_launch(void* const* d_in, const int* in_sizes, int n_in,
                              void* d_out, int out_size, void* d_ws, size_t ws_size,
                              hipStream_t stream) {
    const int*   x     = (const int*)  d_in[0];
    const float* w_ih0 = (const float*)d_in[1];
    const float* w_hh0 = (const float*)d_in[2];
    const float* w_ih1 = (const float*)d_in[3];
    const float* w_hh1 = (const float*)d_in[4];
    const float* w_lin = (const float*)d_in[5];
    const float* b_lin = (const float*)d_in[6];
    float* out = (float*)d_out;
    _Float16* wsp = (_Float16*)d_ws;

    const int nbatch = in_sizes[0] / 64;

    prep_kernel<<<384, 256, 0, stream>>>(w_hh0, w_ih1, w_hh1, wsp);

    const int blocks = (nbatch + 127) / 128;
    rnn_wf_pipe<<<blocks, 512, 0, stream>>>(x, w_ih0, w_lin, b_lin, wsp, out, nbatch);
}

// Round 20
// 1334.806 us; speedup vs baseline: 1.4200x; 1.0070x over previous
//
#include <hip/hip_runtime.h>
#include <math.h>

#define PI_F 3.14159265358979323846f
#define L2E  1.44269504088896340736f

typedef _Float16 half8 __attribute__((ext_vector_type(8)));
typedef _Float16 half4 __attribute__((ext_vector_type(4)));
typedef _Float16 half2t __attribute__((ext_vector_type(2)));
typedef float f32x4 __attribute__((ext_vector_type(4)));

#define MFMA(a, b, c) __builtin_amdgcn_mfma_f32_16x16x32_f16(a, b, c, 0, 0, 0)
#define OFF_CAT 49152   // halfs: wcat starts after whh0 (3*128*128)
// cvt_pkrtz returns __fp16 ext_vector(2); bit_cast to our _Float16 pair
// (layout-identical) -- r18 lesson: implicit conversion is a compile error.
#define CVT_PK(a, b) __builtin_bit_cast(half2t, __builtin_amdgcn_cvt_pkrtz((a), (b)))

__device__ __forceinline__ float rcp_fast(float x) { return __builtin_amdgcn_rcpf(x); }
__device__ __forceinline__ float exp2_fast(float x) { return __builtin_amdgcn_exp2f(x); }
// Exp2-domain gates: pre-activations arrive PRE-SCALED (R/Z by log2e, N by
// 2*log2e, folded into the weights at prep). exp2_fast lowers to one
// v_exp_f32 (r16 lesson: library exp2f() is the precise OCML expansion --
// multi-inst + spill, 24% regression).
__device__ __forceinline__ float sigmoid_y(float y) {   // y = x*log2e
    float e = exp2_fast(-y);                            // neg = free src modifier
    return rcp_fast(1.0f + e);
}
// tanh via 2*sigma(2x)-1 -- 4 ops (exp2, add, rcp, fma), no abs/select.
__device__ __forceinline__ float tanh_y(float y) {      // y = 2x*log2e
    float e = exp2_fast(-y);
    return fmaf(2.0f, rcp_fast(1.0f + e), -1.0f);
}

// Prep: f16 weights, gate-scaled (R/Z x log2e, N x 2log2e) BEFORE rounding;
// concat [w_ih1|w_hh1] along K for layer 1.
__global__ void prep_kernel(const float* __restrict__ whh0,
                            const float* __restrict__ wih1,
                            const float* __restrict__ whh1,
                            _Float16* __restrict__ wsp) {
    int i = blockIdx.x * 256 + threadIdx.x;
    if (i < 49152) {
        float sc = ((i >> 7) >= 256) ? (2.0f * L2E) : L2E;
        wsp[i] = (_Float16)(whh0[i] * sc);
    }
    if (i < 98304) {
        int n = i >> 8, k = i & 255;
        float v = (k < 128) ? wih1[(n << 7) + k] : whh1[(n << 7) + k - 128];
        float sc = (n >= 256) ? (2.0f * L2E) : L2E;
        wsp[OFF_CAT + i] = (_Float16)(v * sc);
    }
}

// 512 threads (8 waves), 128 elems/block, 1 block/CU (LDS 136KB), 2
// waves/SIMD, 256 regs. r19 structure (best, 1344us): 16 dims/wave both
// layers, weights resident (144 regs, "+v"-pinned), own-dim h state in f32
// registers, f16 h planes in LDS, exp2-domain gates + 2sigma-1 tanh +
// packed-RTZ f16 conversion, 2 barriers/tick
//     { A: h0(t) | bar | B: h1(t) | bar | head(t) }.
// Falsified levers (do not revisit): barrier fusion (r3/r7/r9), layer-split
// waves (r6), AGPR pins (r10), half-tick interleave (r12), x-barrier
// prefetch (r13), distributed head (r14), library exp2f (r16). Occupancy
// locked at 2 waves/SIMD; LDS maxed. Winning lever class: work reduction
// (r8 -29%, r11 -7%, r15 -1%, r17 -6%, r19 -6.5%).
//
// Round-20: s_setprio(1) around each eb's MFMA kc-run (catalog T5). The two
// waves per SIMD drift within a barrier window (one in MFMA, one in the
// transcendental epilogue) -> role diversity makes priority arbitration
// meaningful (m191 attn +4-7%; m190's null was pure lockstep). Zero
// numerical risk. Precommit: dur >= ~1335 falsifies the last scheduling
// lever -> declare structural floor.
//
// h planes (128 elems) in MFMA-B-frag chunk order, double-buffered:
//   plane[buf][(kc*8 + eb)*512 + (qd*16 + l4)*8 + j] = h[e=eb*16+l4][dim=32kc+8qd+j]

__global__ void __launch_bounds__(512, 2) rnn_wf_pipe(
    const int*   __restrict__ x,
    const float* __restrict__ w_ih0,
    const float* __restrict__ w_lin,
    const float* __restrict__ b_lin,
    const _Float16* __restrict__ wsp,
    float*       __restrict__ out,
    int nbatch)
{
    __shared__ _Float16 h0[2][16384], h1[2][16384];
    __shared__ float gi0T[2][3][128];          // [prev-bit][gate][dim], gate-scaled
    __shared__ float wlinT[256];               // w_lin flat
    __shared__ unsigned long long bmk[128];    // per-element bit mask

    const int t    = threadIdx.x;
    const int wv   = t >> 6;                   // 0..7 = dim-block (16 dims)
    const int l4   = t & 15;
    const int q    = (t >> 4) & 3;
    const int ebg  = blockIdx.x * 128;

    // ---- init LDS ----
    for (int i = t; i < 16384; i += 512) {     // 16384 ints = 2 bufs x 16384 halfs per array
        ((int*)h0)[i] = 0; ((int*)h1)[i] = 0;
    }
    for (int i = t; i < 768; i += 512) {
        int b = i / 384, rem = i - b * 384;
        float sc = (rem >= 256) ? (2.0f * L2E) : L2E;
        ((float*)gi0T)[b * 384 + rem] = w_ih0[rem * 2 + b] * sc;
    }
    if (t < 256) wlinT[t] = w_lin[t];
    {   // bit masks: thread t -> element t>>2 (0..127), quarter t&3
        int el = t >> 2, qq = t & 3;
        int eg = ebg + el; if (eg >= nbatch) eg = nbatch - 1;
        const int* xr = x + (size_t)eg * 64 + qq * 16;
        unsigned long long m = 0ull;
#pragma unroll
        for (int i = 0; i < 16; ++i)
            m |= ((unsigned long long)((unsigned)(xr[i] + 1) >> 1)) << (qq * 16 + i);
        m |= __shfl_xor(m, 1);
        m |= __shfl_xor(m, 2);
        if (qq == 0) bmk[el] = m;
    }

    const int lo8 = ((q << 4) + l4) << 3;      // = lane*8 halfs: B-frag chunk offset
    const int d0  = wv * 16 + 4 * q;           // first of 4 dims this lane updates
    const int epb = (d0 >> 5) * 4096 + ((d0 >> 3) & 3) * 128 + l4 * 8 + (d0 & 7);

    // ---- register-resident weights (gate-scaled in prep) ----
    half8 w0[3][4];                            // 48 regs
#pragma unroll
    for (int g = 0; g < 3; ++g)
#pragma unroll
        for (int kc = 0; kc < 4; ++kc)
            w0[g][kc] = *(const half8*)(wsp + (size_t)(g * 128 + 16 * wv + l4) * 128 + 32 * kc + 8 * q);
    half8 w1[3][8];                            // 96 regs
#pragma unroll
    for (int g = 0; g < 3; ++g)
#pragma unroll
        for (int kc = 0; kc < 8; ++kc)
            w1[g][kc] = *(const half8*)(wsp + OFF_CAT + (size_t)(g * 128 + 16 * wv + l4) * 256 + 32 * kc + 8 * q);

    // ---- own-dim h state in f32 registers (statically indexed) ----
    f32x4 h0s[8], h1s[8];
#pragma unroll
    for (int eb = 0; eb < 8; ++eb) {
        h0s[eb] = (f32x4){0.f, 0.f, 0.f, 0.f};
        h1s[eb] = (f32x4){0.f, 0.f, 0.f, 0.f};
    }

    // head state (all 8 waves, q-replicated): wave wv owns elems wv*16..+15
    float amp = 1.0f, phs = 0.0f, nu = 0.0f, nd = 0.0f;
    const float bl0 = b_lin[0], bl1 = b_lin[1];
    const int eh = (wv << 4) + l4;

    __syncthreads();

    for (int tick = 0; tick < 64; ++tick) {
        const int cur = tick & 1, prv = cur ^ 1;

        // pin weights: opaque loop-carried registers (no remat from memory)
#pragma unroll
        for (int g = 0; g < 3; ++g) {
#pragma unroll
            for (int kc = 0; kc < 4; ++kc) asm volatile("" : "+v"(w0[g][kc]));
#pragma unroll
            for (int kc = 0; kc < 8; ++kc) asm volatile("" : "+v"(w1[g][kc]));
        }

        // ---- Phase A: h0(tick) = GRU0(onehot(bit(tick-1)), h0(tick-1)) ----
#pragma unroll
        for (int eb = 0; eb < 8; ++eb) {
            f32x4 aR = {0,0,0,0}, aZ = {0,0,0,0}, aN = {0,0,0,0};
            __builtin_amdgcn_s_setprio(1);     // favor MFMA run vs co-wave epilogue
#pragma unroll
            for (int kc = 0; kc < 4; ++kc) {
                const int cb = (kc * 8 + eb) * 512 + lo8;
                half8 hh = *(const half8*)&h0[prv][cb];
                aR = MFMA(w0[0][kc], hh, aR);
                aZ = MFMA(w0[1][kc], hh, aZ);
                aN = MFMA(w0[2][kc], hh, aN);
            }
            __builtin_amdgcn_s_setprio(0);
            const int e = eb * 16 + l4;
            f32x4 giR = {0,0,0,0}, giZ = {0,0,0,0}, giN = {0,0,0,0};
            if (tick > 0) {
                int pb = (int)((bmk[e] >> (tick - 1)) & 1ull);
                const float* gp = &gi0T[pb][0][0];
                giR = *(const f32x4*)(gp + d0);
                giZ = *(const f32x4*)(gp + 128 + d0);
                giN = *(const f32x4*)(gp + 256 + d0);
            }
            const int ep_ = epb + eb * 512;
            f32x4 hp = h0s[eb];
            f32x4 hnv;
#pragma unroll
            for (int r = 0; r < 4; ++r) {
                float rr = sigmoid_y(giR[r] + aR[r]);
                float zz = sigmoid_y(giZ[r] + aZ[r]);
                float nn = tanh_y(giN[r] + rr * aN[r]);
                hnv[r] = nn + zz * (hp[r] - nn);
            }
            h0s[eb] = hnv;
            half2t pa  = CVT_PK(hnv[0], hnv[1]);
            half2t pb2 = CVT_PK(hnv[2], hnv[3]);
            half4 nh;
            nh[0] = pa[0]; nh[1] = pa[1]; nh[2] = pb2[0]; nh[3] = pb2[1];
            *(half4*)&h0[cur][ep_] = nh;
        }

        __syncthreads();

        // ---- Phase B: h1(tick) = GRU1(h0(tick), h1(tick-1)) ----
#pragma unroll
        for (int eb = 0; eb < 8; ++eb) {
            f32x4 aR = {0,0,0,0}, aZ = {0,0,0,0};
            f32x4 aNi = {0,0,0,0}, aNh = {0,0,0,0};
            __builtin_amdgcn_s_setprio(1);
#pragma unroll
            for (int kc = 0; kc < 8; ++kc) {
                const int cb = ((kc & 3) * 8 + eb) * 512 + lo8;
                half8 hh;
                if (kc < 4) hh = *(const half8*)&h0[cur][cb];
                else        hh = *(const half8*)&h1[prv][cb];
                aR = MFMA(w1[0][kc], hh, aR);
                aZ = MFMA(w1[1][kc], hh, aZ);
                if (kc < 4) aNi = MFMA(w1[2][kc], hh, aNi);
                else        aNh = MFMA(w1[2][kc], hh, aNh);
            }
            __builtin_amdgcn_s_setprio(0);
            const int ep_ = epb + eb * 512;
            f32x4 hp = h1s[eb];
            f32x4 hnv;
#pragma unroll
            for (int r = 0; r < 4; ++r) {
                float rr = sigmoid_y(aR[r]);
                float zz = sigmoid_y(aZ[r]);
                float nn = tanh_y(aNi[r] + rr * aNh[r]);
                hnv[r] = nn + zz * (hp[r] - nn);
            }
            h1s[eb] = hnv;
            half2t pa  = CVT_PK(hnv[0], hnv[1]);
            half2t pb2 = CVT_PK(hnv[2], hnv[3]);
            half4 nh;
            nh[0] = pa[0]; nh[1] = pa[1]; nh[2] = pb2[0]; nh[3] = pb2[1];
            *(half4*)&h1[cur][ep_] = nh;
        }

        __syncthreads();

        // ---- head for step s = tick; h1(s) in buf cur.  ALL 8 waves, each
        //      owning its 16 elems. Lane-linear reads (conflict-free);
        //      xor-16/32 reduce combines q-groups. ----
        {
            const int s = tick;
            float l0 = 0.0f, l1 = 0.0f;
#pragma unroll
            for (int ks = 0; ks < 4; ++ks) {
                const int cb = (ks * 8 + wv) * 512 + lo8;
                half8 hh = *(const half8*)&h1[cur][cb];
                const float* wpl = &wlinT[32 * ks + 8 * q];
#pragma unroll
                for (int j = 0; j < 8; ++j) {
                    float hv = (float)hh[j];
                    l0 = fmaf(hv, wpl[j], l0);
                    l1 = fmaf(hv, wpl[128 + j], l1);
                }
            }
            l0 += __shfl_xor(l0, 16); l0 += __shfl_xor(l0, 32); l0 += bl0;
            l1 += __shfl_xor(l1, 16); l1 += __shfl_xor(l1, 32); l1 += bl1;

            // head keeps exact reference-form math (unscaled logits)
            float e01 = __expf(-(l0 - l1));
            float p0 = rcp_fast(1.0f + e01);
            float e10 = __expf(-(l1 - l0));
            float p1 = rcp_fast(1.0f + e10);
            float y0 = sqrtf(p0), y1 = sqrtf(p1);
            float ph0 = PI_F * l0 * rcp_fast(1.0f + fabsf(l0));
            float ph1 = PI_F * l1 * rcp_fast(1.0f + fabsf(l1));

            int bit = (int)((bmk[eh] >> s) & 1ull);
            bool is_even = (s & 1) == 0;
            float num   = is_even ? nu : nd;
            float lower = -16.0f + (float)(s >> 1);
            float occ   = (num < 16.0f) ? 1.0f : 0.0f;
            float unocc = (num > lower) ? 1.0f : 0.0f;
            if (s >= 16) {
                float m0 = y0 * unocc, m1 = y1 * occ;
                float nrm = fmaxf(sqrtf(m0 * m0 + m1 * m1), 1e-12f);
                float rn  = rcp_fast(nrm);
                y0 = m0 * rn; y1 = m1 * rn;
            }
            if (is_even) nu += (float)bit; else nd += (float)bit;
            amp *= bit ? y1 : y0;
            phs += bit ? ph1 : ph0;
        }
    }

    if (q == 0) {
        int eg = ebg + eh;
        if (eg < nbatch) {
            float s, c;
            sincosf(phs, &s, &c);
            out[eg]          = amp * c;
            out[nbatch + eg] = amp * s;
        }
    }
}

extern "C" void kernel_launch(void* const* d_in, const int* in_sizes, int n_in,
                              void* d_out, int out_size, void* d_ws, size_t ws_size,
                              hipStream_t stream) {
    const int*   x     = (const int*)  d_in[0];
    const float* w_ih0 = (const float*)d_in[1];
    const float* w_hh0 = (const float*)d_in[2];
    const float* w_ih1 = (const float*)d_in[3];
    const float* w_hh1 = (const float*)d_in[4];
    const float* w_lin = (const float*)d_in[5];
    const float* b_lin = (const float*)d_in[6];
    float* out = (float*)d_out;
    _Float16* wsp = (_Float16*)d_ws;

    const int nbatch = in_sizes[0] / 64;

    prep_kernel<<<384, 256, 0, stream>>>(w_hh0, w_ih1, w_hh1, wsp);

    const int blocks = (nbatch + 127) / 128;
    rnn_wf_pipe<<<blocks, 512, 0, stream>>>(x, w_ih0, w_lin, b_lin, wsp, out, nbatch);
}